// Round 1
// baseline (444.856 us; speedup 1.0000x reference)
//
#include <hip/hip_runtime.h>

#define BIGF 1e30f

constexpr int NB = 16;    // batches
constexpr int NN = 512;   // N rows
constexpr int MM = 512;   // M cols
constexpr int KD = 64;    // feature dim
constexpr int WAVES = 8;
constexpr int CSPAN = 64;                          // diagonals per barrier phase
constexpr int NSPANS = (NN + MM - 1 + CSPAN - 1) / CSPAN;  // 16
constexpr int TPHASES = NSPANS + WAVES - 1;        // 23
constexpr int PF = 8;                              // prefetch depth (steps)

// ---------------- Kernel 1: pairwise squared distances ----------------
// D[b][i][j] = min( sum_d (X[b,i,d]-Y[b,j,d])^2 , 1e4 ), row-major 512x512.
__global__ __launch_bounds__(256) void pairdist_kernel(
    const float* __restrict__ X, const float* __restrict__ Y,
    float* __restrict__ D) {
  const int b = blockIdx.z;
  const int i0 = blockIdx.y * 64;
  const int j0 = blockIdx.x * 64;

  __shared__ float Xs[64][65];
  __shared__ float Ys[64][65];

  const float* Xb = X + ((size_t)b * NN + i0) * KD;
  const float* Yb = Y + ((size_t)b * MM + j0) * KD;
  for (int k = threadIdx.x; k < 64 * KD; k += 256) {
    Xs[k >> 6][k & 63] = Xb[k];
    Ys[k >> 6][k & 63] = Yb[k];
  }
  __syncthreads();

  const int tx = threadIdx.x & 15;
  const int ty = threadIdx.x >> 4;
  const int r0 = ty * 4, c0 = tx * 4;

  float acc[4][4];
#pragma unroll
  for (int a = 0; a < 4; ++a)
#pragma unroll
    for (int e = 0; e < 4; ++e) acc[a][e] = 0.0f;

  for (int d = 0; d < KD; ++d) {
    float xv[4], yv[4];
#pragma unroll
    for (int q = 0; q < 4; ++q) xv[q] = Xs[r0 + q][d];
#pragma unroll
    for (int q = 0; q < 4; ++q) yv[q] = Ys[c0 + q][d];
#pragma unroll
    for (int a = 0; a < 4; ++a)
#pragma unroll
      for (int e = 0; e < 4; ++e) {
        float df = xv[a] - yv[e];
        acc[a][e] = fmaf(df, df, acc[a][e]);
      }
  }

  float* Db = D + (((size_t)b * NN + i0) * MM) + j0;
#pragma unroll
  for (int a = 0; a < 4; ++a) {
    float4 v;
    v.x = fminf(acc[a][0], 10000.0f);
    v.y = fminf(acc[a][1], 10000.0f);
    v.z = fminf(acc[a][2], 10000.0f);
    v.w = fminf(acc[a][3], 10000.0f);
    *reinterpret_cast<float4*>(&Db[(size_t)(r0 + a) * MM + c0]) = v;
  }
}

// ---------------- Kernel 2: soft-DTW wavefront DP ----------------
// One block per batch. Thread t owns row i=t+1. Anti-diagonal sweep;
// intra-wave neighbor values via ds_bpermute, inter-wave via LDS row buffer
// with one barrier per 64-diagonal span (waves skewed by one span each).
__global__ __launch_bounds__(512) void softdtw_kernel(
    const float* __restrict__ D, float* __restrict__ out) {
  const int b = blockIdx.x;
  const int t = threadIdx.x;       // row index 0..511 (i = t+1)
  const int w = t >> 6;            // wave id 0..7
  const int lane = t & 63;

  const float* __restrict__ Drow = D + ((size_t)b * NN + t) * MM;

  // buf[w][j] = R[64w][j] (row above wave w), published by wave w-1 lane 63.
  __shared__ float buf[WAVES][MM + 2];
  for (int k = t; k < WAVES * (MM + 2); k += NN) (&buf[0][0])[k] = BIGF;
  __syncthreads();

  const int bpaddr = ((lane - 1) & 63) << 2;  // ds_bpermute src = lane-1

  float r_a = BIGF;  // own R[i][j-1]
  float r_b = BIGF;  // own R[i][j-2]

  float pre[PF];
#pragma unroll
  for (int k = 0; k < PF; ++k) {
    int idx = k - t;
    idx = idx < 0 ? 0 : (idx > MM - 1 ? MM - 1 : idx);
    pre[k] = Drow[idx];
  }

  for (int S = 0; S < TPHASES; ++S) {
    const int c = S - w;  // this wave's span index
    if (c >= 0 && c < NSPANS) {
      const int pbase = c * CSPAN;
      for (int su = 0; su < CSPAN; su += PF) {
#pragma unroll
        for (int k = 0; k < PF; ++k) {
          const int p = pbase + su + k;     // global diagonal index
          const int j = p + 1 - t;          // my column this step
          const bool active = (j >= 1) && (j <= MM);

          const float dval = pre[k];
          // refill ring: value for step p+PF (own row is contiguous in j)
          int nidx = p + PF - t;
          nidx = nidx < 0 ? 0 : (nidx > MM - 1 ? MM - 1 : nidx);
          pre[k] = Drow[nidx];

          // neighbor (row i-1) values: up1 = R[i-1][j], up2 = R[i-1][j-1]
          float up1 = __int_as_float(
              __builtin_amdgcn_ds_bpermute(bpaddr, __float_as_int(r_a)));
          float up2 = __int_as_float(
              __builtin_amdgcn_ds_bpermute(bpaddr, __float_as_int(r_b)));
          if (lane == 0) {
            if (w == 0) {
              up1 = BIGF;                         // R[0][j]   (j>=1) = inf
              up2 = (j == 1) ? 0.0f : BIGF;       // R[0][j-1]: only R[0][0]=0
            } else {
              int jc = j < 1 ? 1 : (j > MM ? MM : j);
              up1 = buf[w][jc];
              up2 = buf[w][jc - 1];
            }
          }

          // softmin(r0,r1,r2) = m - log(sum exp(m - r))  (gamma = 1)
          const float m = fminf(fminf(up1, up2), r_a);
          const float sum =
              __expf(m - up1) + __expf(m - up2) + __expf(m - r_a);
          const float newv = dval + (m - __logf(sum));

          if (w < WAVES - 1) {
            if (lane == 63 && active) buf[w + 1][j] = newv;
          }
          r_b = active ? r_a : r_b;
          r_a = active ? newv : r_a;
        }
      }
    }
    __syncthreads();
  }

  if (t == NN - 1) out[b] = r_a;  // R[512][512]
}

extern "C" void kernel_launch(void* const* d_in, const int* in_sizes, int n_in,
                              void* d_out, int out_size, void* d_ws,
                              size_t ws_size, hipStream_t stream) {
  const float* X = (const float*)d_in[0];
  const float* Y = (const float*)d_in[1];
  float* out = (float*)d_out;
  float* D = (float*)d_ws;

  const size_t needed = (size_t)NB * NN * MM * sizeof(float);
  if (ws_size < needed) return;  // ws too small: leave output poisoned (fail loudly)

  pairdist_kernel<<<dim3(MM / 64, NN / 64, NB), 256, 0, stream>>>(X, Y, D);
  softdtw_kernel<<<NB, NN, 0, stream>>>(D, out);
}

// Round 2
// 280.478 us; speedup vs baseline: 1.5861x; 1.5861x over previous
//
#include <hip/hip_runtime.h>

#define BIGF 1e30f
#define LOG2E 1.4426950408889634f
#define LN2F 0.6931471805599453f

constexpr int NB = 16;    // batches
constexpr int NN = 512;   // N rows
constexpr int MM = 512;   // M cols
constexpr int KD = 64;    // feature dim
constexpr int WAVES = 4;                     // 256 threads, 2 rows/lane
constexpr int NSPANS = 16;                   // (N+M-1)/64 rounded up
constexpr int TPH = NSPANS + WAVES - 1;      // 19 barrier phases

// ---------------- Kernel 1: pairwise squared distances (exp2-domain) -------
// D'[b][i][j] = min( sum_d (X[b,i,d]-Y[b,j,d])^2 , 1e4 ) * log2(e)
__global__ __launch_bounds__(256) void pairdist_kernel(
    const float* __restrict__ X, const float* __restrict__ Y,
    float* __restrict__ D) {
  const int b = blockIdx.z;
  const int i0 = blockIdx.y * 64;
  const int j0 = blockIdx.x * 64;

  __shared__ float Xs[64][65];
  __shared__ float Ys[64][65];

  const float* Xb = X + ((size_t)b * NN + i0) * KD;
  const float* Yb = Y + ((size_t)b * MM + j0) * KD;
  for (int k = threadIdx.x; k < 64 * KD; k += 256) {
    Xs[k >> 6][k & 63] = Xb[k];
    Ys[k >> 6][k & 63] = Yb[k];
  }
  __syncthreads();

  const int tx = threadIdx.x & 15;
  const int ty = threadIdx.x >> 4;
  const int r0 = ty * 4, c0 = tx * 4;

  float acc[4][4];
#pragma unroll
  for (int a = 0; a < 4; ++a)
#pragma unroll
    for (int e = 0; e < 4; ++e) acc[a][e] = 0.0f;

  for (int d = 0; d < KD; ++d) {
    float xv[4], yv[4];
#pragma unroll
    for (int q = 0; q < 4; ++q) xv[q] = Xs[r0 + q][d];
#pragma unroll
    for (int q = 0; q < 4; ++q) yv[q] = Ys[c0 + q][d];
#pragma unroll
    for (int a = 0; a < 4; ++a)
#pragma unroll
      for (int e = 0; e < 4; ++e) {
        float df = xv[a] - yv[e];
        acc[a][e] = fmaf(df, df, acc[a][e]);
      }
  }

  float* Db = D + (((size_t)b * NN + i0) * MM) + j0;
#pragma unroll
  for (int a = 0; a < 4; ++a) {
    float4 v;
    v.x = fminf(acc[a][0], 10000.0f) * LOG2E;
    v.y = fminf(acc[a][1], 10000.0f) * LOG2E;
    v.z = fminf(acc[a][2], 10000.0f) * LOG2E;
    v.w = fminf(acc[a][3], 10000.0f) * LOG2E;
    *reinterpret_cast<float4*>(&Db[(size_t)(r0 + a) * MM + c0]) = v;
  }
}

// DPP wave_shr:1 — lane i gets lane i-1's value; lane 0 gets `fill`.
__device__ __forceinline__ float dpp_shr1(float v, float fill) {
  return __int_as_float(__builtin_amdgcn_update_dpp(
      __float_as_int(fill), __float_as_int(v), 0x138 /*WAVE_SHR1*/, 0xf, 0xf,
      false));
}

// ---------------- Kernel 2: soft-DTW wavefront DP (base-2 domain) ----------
// One block per batch, 4 waves x 64 lanes, 2 adjacent rows per lane.
// Recurrence chain uses only VALU (DPP + exp2/log2); LDS only at phase
// boundaries (boundary row broadcast + lane-63 publish).
__global__ __launch_bounds__(256) void softdtw_kernel(
    const float* __restrict__ D, float* __restrict__ out) {
  const int b = blockIdx.x;
  const int t = threadIdx.x;
  const int w = t >> 6;
  const int lane = t & 63;

  // buf[w][j] = R'[128w][j] (boundary row above wave w), w = 1..3 used.
  __shared__ float buf[WAVES][MM + 2];
  for (int k = t; k < WAVES * (MM + 2); k += 256) (&buf[0][0])[k] = BIGF;
  __syncthreads();

  const int i0 = 128 * w + 2 * lane + 1;  // 1-based top row of this lane
  const float* __restrict__ Dp0 = D + ((size_t)b * NN + (i0 - 1)) * MM;
  const float* __restrict__ Dp1 = Dp0 + MM;

  float ra0 = BIGF, rb0 = BIGF;  // row i0:  R'[i0][j-1], R'[i0][j-2]
  float ra1 = BIGF, rb1 = BIGF;  // row i0+1
  float old2 = BIGF;             // lane-0 up2 boundary (chained)
  float ring0[8], ring1[8];
  int jv = 0, qc = 0;

  for (int S = 0; S < TPH; ++S) {
    const int c = S - w;  // this wave's span of 64 diagonals
    if (c >= 2 * w && c <= 2 * w + 9 && c < NSPANS) {
      if (c == 2 * w) {  // first worked phase: init streams
        jv = 1 - 2 * lane;  // j of row i0 at step 0
        qc = jv - 1;        // D column index
#pragma unroll
        for (int kk = 0; kk < 8; ++kk) {
          int c0 = qc + kk;     c0 = c0 < 0 ? 0 : (c0 > MM - 1 ? MM - 1 : c0);
          int c1 = qc - 1 + kk; c1 = c1 < 0 ? 0 : (c1 > MM - 1 ? MM - 1 : c1);
          ring0[kk] = Dp0[c0];
          ring1[kk] = Dp1[c1];
        }
      }
      // boundary row segment for this phase (only lane-0 consumes, via
      // readlane; garbage beyond clamp is masked by `active`)
      float browA;
      if (w) {
        int bi = 64 * (c - 2 * w) + 1 + lane;
        bi = bi > MM + 1 ? MM + 1 : bi;
        browA = buf[w][bi];
      } else {
        browA = BIGF;
      }
      for (int su = 0; su < 64; su += 8) {
#pragma unroll
        for (int kk = 0; kk < 8; ++kk) {
          // lane-0 boundary values (uniform)
          float o1 = __int_as_float(__builtin_amdgcn_readlane(
              __float_as_int(browA), su + kk));
          float o2 = old2;
          if (kk == 0 && w == 0 && c == 0 && su == 0) o2 = 0.0f;  // R'[0][0]
          old2 = o1;

          // neighbor row (i0-1) values via DPP from lane-1's bottom row
          float up1 = dpp_shr1(ra1, o1);  // R'[i0-1][j]
          float up2 = dpp_shr1(rb1, o2);  // R'[i0-1][j-1]

          // row i0 cell
          float d0 = ring0[kk];
          float m0 = fminf(fminf(up1, up2), ra0);
          float s0 = __builtin_amdgcn_exp2f(m0 - up1) +
                     __builtin_amdgcn_exp2f(m0 - up2) +
                     __builtin_amdgcn_exp2f(m0 - ra0);
          float n0 = d0 + (m0 - __builtin_amdgcn_logf(s0));

          // row i0+1 cell (uses pre-update row-i0 state)
          float d1 = ring1[kk];
          float m1 = fminf(fminf(ra0, rb0), ra1);
          float s1 = __builtin_amdgcn_exp2f(m1 - ra0) +
                     __builtin_amdgcn_exp2f(m1 - rb0) +
                     __builtin_amdgcn_exp2f(m1 - ra1);
          float n1 = d1 + (m1 - __builtin_amdgcn_logf(s1));

          bool a0 = (unsigned)(jv - 1) < (unsigned)MM;
          bool a1 = (unsigned)(jv - 2) < (unsigned)MM;

          // refill prefetch rings (clamped; clamp only alters inactive slots)
          int rc0 = qc + 8; rc0 = rc0 < 0 ? 0 : (rc0 > MM - 1 ? MM - 1 : rc0);
          int rc1 = qc + 7; rc1 = rc1 < 0 ? 0 : (rc1 > MM - 1 ? MM - 1 : rc1);
          ring0[kk] = Dp0[rc0];
          ring1[kk] = Dp1[rc1];
          qc++;

          rb0 = a0 ? ra0 : rb0;
          ra0 = a0 ? n0 : ra0;
          rb1 = a1 ? ra1 : rb1;
          ra1 = a1 ? n1 : ra1;

          // publish boundary row for next wave (row 128(w+1) = lane63.i1)
          if (w < WAVES - 1 && lane == 63 && a1) buf[w + 1][jv - 1] = n1;
          jv++;
        }
      }
    }
    __syncthreads();
  }

  if (t == 255) out[b] = ra1 * LN2F;  // R'[512][512] -> natural-log domain
}

extern "C" void kernel_launch(void* const* d_in, const int* in_sizes, int n_in,
                              void* d_out, int out_size, void* d_ws,
                              size_t ws_size, hipStream_t stream) {
  const float* X = (const float*)d_in[0];
  const float* Y = (const float*)d_in[1];
  float* out = (float*)d_out;
  float* D = (float*)d_ws;

  const size_t needed = (size_t)NB * NN * MM * sizeof(float);
  if (ws_size < needed) return;

  pairdist_kernel<<<dim3(MM / 64, NN / 64, NB), 256, 0, stream>>>(X, Y, D);
  softdtw_kernel<<<NB, 256, 0, stream>>>(D, out);
}

// Round 3
// 201.926 us; speedup vs baseline: 2.2031x; 1.3890x over previous
//
#include <hip/hip_runtime.h>

#define BIGF 1e30f
#define LOG2E 1.4426950408889634f
#define LN2F 0.6931471805599453f

constexpr int NB = 16;    // batches
constexpr int NN = 512;   // N rows
constexpr int MM = 512;   // M cols
constexpr int KD = 64;    // feature dim
constexpr int WAVES = 4;                     // 256 threads, 2 rows/lane
constexpr int NSPANS = 16;                   // (N+M-1)/64 rounded up
constexpr int TPH = NSPANS + WAVES - 1;      // 19 barrier phases
constexpr int DIAGELEMS = NN * MM;           // packed diag layout, per batch

// Packed anti-diagonal layout: element (i,j) [0-based] lives at
// Dsk[b*DIAGELEMS + B(s) + i],  s = i+j,  B(s) = prefix(diag lengths) - rmin(s).
__device__ __forceinline__ int Bclosed(int s) {
  return (s <= 511) ? (s * (s + 1)) / 2
                    : DIAGELEMS - ((1023 - s) * (1024 - s)) / 2 - (s - 511);
}

// ---------------- Kernel 1: pairwise squared distances (exp2-domain) -------
// Dsk[(s,i)] = min( sum_d (X[b,i,d]-Y[b,j,d])^2 , 1e4 ) * log2(e)
__global__ __launch_bounds__(256) void pairdist_kernel(
    const float* __restrict__ X, const float* __restrict__ Y,
    float* __restrict__ Dsk) {
  const int b = blockIdx.z;
  const int i0 = blockIdx.y * 64;
  const int j0 = blockIdx.x * 64;

  __shared__ float Xs[64][65];
  __shared__ float Ys[64][65];

  const float* Xb = X + ((size_t)b * NN + i0) * KD;
  const float* Yb = Y + ((size_t)b * MM + j0) * KD;
  for (int k = threadIdx.x; k < 64 * KD; k += 256) {
    Xs[k >> 6][k & 63] = Xb[k];
    Ys[k >> 6][k & 63] = Yb[k];
  }
  __syncthreads();

  const int tx = threadIdx.x & 15;
  const int ty = threadIdx.x >> 4;
  const int r0 = ty * 4, c0 = tx * 4;

  float acc[4][4];
#pragma unroll
  for (int a = 0; a < 4; ++a)
#pragma unroll
    for (int e = 0; e < 4; ++e) acc[a][e] = 0.0f;

  for (int d = 0; d < KD; ++d) {
    float xv[4], yv[4];
#pragma unroll
    for (int q = 0; q < 4; ++q) xv[q] = Xs[r0 + q][d];
#pragma unroll
    for (int q = 0; q < 4; ++q) yv[q] = Ys[c0 + q][d];
#pragma unroll
    for (int a = 0; a < 4; ++a)
#pragma unroll
      for (int e = 0; e < 4; ++e) {
        float df = xv[a] - yv[e];
        acc[a][e] = fmaf(df, df, acc[a][e]);
      }
  }

  float* Db = Dsk + (size_t)b * DIAGELEMS;
#pragma unroll
  for (int a = 0; a < 4; ++a) {
    const int i = i0 + r0 + a;
#pragma unroll
    for (int e = 0; e < 4; ++e) {
      const int j = j0 + c0 + e;
      Db[Bclosed(i + j) + i] = fminf(acc[a][e], 10000.0f) * LOG2E;
    }
  }
}

// DPP wave_shr:1 — lane i gets lane i-1's value; lane 0 gets `fill`.
__device__ __forceinline__ float dpp_shr1(float v, float fill) {
  return __int_as_float(__builtin_amdgcn_update_dpp(
      __float_as_int(fill), __float_as_int(v), 0x138 /*WAVE_SHR1*/, 0xf, 0xf,
      false));
}

// ---------------- Kernel 2: soft-DTW wavefront DP (base-2 domain) ----------
// One block per batch, 4 waves x 64 lanes, 2 adjacent rows per lane.
// Recurrence chain uses only VALU (DPP + exp2/log2); D refills are fully
// coalesced thanks to the packed anti-diagonal layout; LDS only at phase
// boundaries (boundary row broadcast + lane-63 publish).
__global__ __launch_bounds__(256) void softdtw_kernel(
    const float* __restrict__ Dsk, float* __restrict__ out) {
  const int b = blockIdx.x;
  const int t = threadIdx.x;
  const int w = t >> 6;
  const int lane = t & 63;

  // buf[w][j] = R'[128w][j] (boundary row above wave w), w = 1..3 used.
  __shared__ float buf[WAVES][MM + 2];
  for (int k = t; k < WAVES * (MM + 2); k += 256) (&buf[0][0])[k] = BIGF;
  __syncthreads();

  const int r0 = 128 * w + 2 * lane;  // 0-based top row of this lane
  const float* __restrict__ Dskb = Dsk + (size_t)b * DIAGELEMS;

  float ra0 = BIGF, rb0 = BIGF;  // row r0 (1-based i0):  R'[i0][j-1], R'[i0][j-2]
  float ra1 = BIGF, rb1 = BIGF;  // row r0+1
  float old2 = BIGF;             // lane-0 up2 boundary (chained)
  float ring0[8], ring1[8];
  int jv = 0;
  int sfut = 0, Bfut = 0;  // prefetch stream: next diag index + its base

  for (int S = 0; S < TPH; ++S) {
    const int c = S - w;  // this wave's span of 64 diagonals
    if (c >= 2 * w && c <= 2 * w + 9 && c < NSPANS) {
      if (c == 2 * w) {  // first worked phase: init streams
        jv = 1 - 2 * lane;  // j of row i0 at step 0
        sfut = 128 * w;
        Bfut = Bclosed(sfut);
#pragma unroll
        for (int kk = 0; kk < 8; ++kk) {
          const float* p = Dskb + __builtin_amdgcn_readfirstlane(Bfut);
          ring0[kk] = p[r0];
          ring1[kk] = p[r0 + 1];
          Bfut += (sfut < 511) ? (sfut + 1)
                               : ((sfut < 1022) ? (1022 - sfut) : 0);
          sfut++;
        }
      }
      // boundary row segment for this phase (only lane-0 consumes, via
      // readlane; garbage beyond clamp is masked by `active`)
      float browA;
      if (w) {
        int bi = 64 * (c - 2 * w) + 1 + lane;
        bi = bi > MM + 1 ? MM + 1 : bi;
        browA = buf[w][bi];
      } else {
        browA = BIGF;
      }
      for (int su = 0; su < 64; su += 8) {
#pragma unroll
        for (int kk = 0; kk < 8; ++kk) {
          // lane-0 boundary values (uniform)
          float o1 = __int_as_float(__builtin_amdgcn_readlane(
              __float_as_int(browA), su + kk));
          float o2 = old2;
          if (kk == 0 && w == 0 && c == 0 && su == 0) o2 = 0.0f;  // R'[0][0]
          old2 = o1;

          // neighbor row (i0-1) values via DPP from lane-1's bottom row
          float up1 = dpp_shr1(ra1, o1);  // R'[i0-1][j]
          float up2 = dpp_shr1(rb1, o2);  // R'[i0-1][j-1]

          // row i0 cell
          float d0 = ring0[kk];
          float m0 = fminf(fminf(up1, up2), ra0);
          float s0 = __builtin_amdgcn_exp2f(m0 - up1) +
                     __builtin_amdgcn_exp2f(m0 - up2) +
                     __builtin_amdgcn_exp2f(m0 - ra0);
          float n0 = d0 + (m0 - __builtin_amdgcn_logf(s0));

          // row i0+1 cell (uses pre-update row-i0 state)
          float d1 = ring1[kk];
          float m1 = fminf(fminf(ra0, rb0), ra1);
          float s1 = __builtin_amdgcn_exp2f(m1 - ra0) +
                     __builtin_amdgcn_exp2f(m1 - rb0) +
                     __builtin_amdgcn_exp2f(m1 - ra1);
          float n1 = d1 + (m1 - __builtin_amdgcn_logf(s1));

          bool a0 = (unsigned)(jv - 1) < (unsigned)MM;
          bool a1 = (unsigned)(jv - 2) < (unsigned)MM;

          // refill prefetch rings: step sfut's (row r0, row r0+1) pair is
          // contiguous at Dskb[Bfut + r0] — coalesced across the wave.
          {
            const float* p = Dskb + __builtin_amdgcn_readfirstlane(Bfut);
            ring0[kk] = p[r0];
            ring1[kk] = p[r0 + 1];
            Bfut += (sfut < 511) ? (sfut + 1)
                                 : ((sfut < 1022) ? (1022 - sfut) : 0);
            sfut++;
          }

          rb0 = a0 ? ra0 : rb0;
          ra0 = a0 ? n0 : ra0;
          rb1 = a1 ? ra1 : rb1;
          ra1 = a1 ? n1 : ra1;

          // publish boundary row for next wave (row 128(w+1) = lane63.i1)
          if (w < WAVES - 1 && lane == 63 && a1) buf[w + 1][jv - 1] = n1;
          jv++;
        }
      }
    }
    __syncthreads();
  }

  if (t == 255) out[b] = ra1 * LN2F;  // R'[512][512] -> natural-log domain
}

extern "C" void kernel_launch(void* const* d_in, const int* in_sizes, int n_in,
                              void* d_out, int out_size, void* d_ws,
                              size_t ws_size, hipStream_t stream) {
  const float* X = (const float*)d_in[0];
  const float* Y = (const float*)d_in[1];
  float* out = (float*)d_out;
  float* Dsk = (float*)d_ws;

  const size_t needed = (size_t)NB * DIAGELEMS * sizeof(float);
  if (ws_size < needed) return;

  pairdist_kernel<<<dim3(MM / 64, NN / 64, NB), 256, 0, stream>>>(X, Y, Dsk);
  softdtw_kernel<<<NB, 256, 0, stream>>>(Dsk, out);
}

// Round 4
// 172.315 us; speedup vs baseline: 2.5816x; 1.1718x over previous
//
#include <hip/hip_runtime.h>

#define BIGF 1e30f
#define LOG2E 1.4426950408889634f
#define LN2F 0.6931471805599453f

constexpr int NB = 16;    // batches
constexpr int NN = 512;   // N rows
constexpr int MM = 512;   // M cols
constexpr int KD = 64;    // feature dim
constexpr int WAVES = 4;                     // 256 threads, 2 rows/lane
constexpr int CSPAN = 32;                    // diagonals per barrier phase
constexpr int NSPANS = 32;                   // (N+M-1)/CSPAN rounded up
constexpr int SPW = 20;                      // spans touched per wave
constexpr int TPH = NSPANS + WAVES - 1;      // 35 barrier phases
constexpr int DIAGELEMS = NN * MM;           // packed diag layout, per batch

// LDS layout (dynamic): bufD[4 waves][2 parity][32 steps][128 rows] + bbuf[4][514]
constexpr int BUFD_FLOATS = WAVES * 2 * CSPAN * 128;  // 32768
constexpr int BBUF_FLOATS = WAVES * (MM + 2);         // 2056
constexpr int SMEM_BYTES = (BUFD_FLOATS + BBUF_FLOATS) * 4;  // 139296

// Packed anti-diagonal layout: element (i,j) [0-based] lives at
// Dsk[b*DIAGELEMS + B(s) + i],  s = i+j.
__device__ __forceinline__ int Bclosed(int s) {
  return (s <= 511) ? (s * (s + 1)) / 2
                    : DIAGELEMS - ((1023 - s) * (1024 - s)) / 2 - (s - 511);
}

// ---------------- Kernel 1: pairwise squared distances (exp2-domain) -------
__global__ __launch_bounds__(256) void pairdist_kernel(
    const float* __restrict__ X, const float* __restrict__ Y,
    float* __restrict__ Dsk) {
  const int b = blockIdx.z;
  const int i0 = blockIdx.y * 64;
  const int j0 = blockIdx.x * 64;

  __shared__ float Xs[64][65];
  __shared__ float Ys[64][65];

  const float* Xb = X + ((size_t)b * NN + i0) * KD;
  const float* Yb = Y + ((size_t)b * MM + j0) * KD;
  for (int k = threadIdx.x; k < 64 * KD; k += 256) {
    Xs[k >> 6][k & 63] = Xb[k];
    Ys[k >> 6][k & 63] = Yb[k];
  }
  __syncthreads();

  const int tx = threadIdx.x & 15;
  const int ty = threadIdx.x >> 4;
  const int r0 = ty * 4, c0 = tx * 4;

  float acc[4][4];
#pragma unroll
  for (int a = 0; a < 4; ++a)
#pragma unroll
    for (int e = 0; e < 4; ++e) acc[a][e] = 0.0f;

  for (int d = 0; d < KD; ++d) {
    float xv[4], yv[4];
#pragma unroll
    for (int q = 0; q < 4; ++q) xv[q] = Xs[r0 + q][d];
#pragma unroll
    for (int q = 0; q < 4; ++q) yv[q] = Ys[c0 + q][d];
#pragma unroll
    for (int a = 0; a < 4; ++a)
#pragma unroll
      for (int e = 0; e < 4; ++e) {
        float df = xv[a] - yv[e];
        acc[a][e] = fmaf(df, df, acc[a][e]);
      }
  }

  float* Db = Dsk + (size_t)b * DIAGELEMS;
#pragma unroll
  for (int a = 0; a < 4; ++a) {
    const int i = i0 + r0 + a;
#pragma unroll
    for (int e = 0; e < 4; ++e) {
      const int j = j0 + c0 + e;
      Db[Bclosed(i + j) + i] = fminf(acc[a][e], 10000.0f) * LOG2E;
    }
  }
}

// DPP wave_shr:1 — lane i gets lane i-1's value; lane 0 gets `fill`.
__device__ __forceinline__ float dpp_shr1(float v, float fill) {
  return __int_as_float(__builtin_amdgcn_update_dpp(
      __float_as_int(fill), __float_as_int(v), 0x138 /*WAVE_SHR1*/, 0xf, 0xf,
      false));
}

// DMA one span's D-block (32 steps x 128 rows) for wave wu into its LDS
// buffer. 16 x global_load_lds width-16: lane l covers step 2u+(l>=32),
// rows 128*wu + (l&31)*4 .. +3. LDS dest is wave-uniform base + lane*16.
__device__ __forceinline__ void dma_span(const float* __restrict__ Dskb,
                                         float* bufD, int wu, int q,
                                         int lane) {
  float* dst0 = bufD + (wu * 2 + (q & 1)) * (CSPAN * 128);
  const int rbase = 128 * wu + (lane & 31) * 4;
  const int hi = (lane >> 5) & 1;
#pragma unroll
  for (int u = 0; u < 16; ++u) {
    int s = 32 * q + 2 * u + hi;
    s = s > 1022 ? 1022 : s;
    int e = Bclosed(s) + rbase;
    e = e > DIAGELEMS - 4 ? DIAGELEMS - 4 : e;  // stay in-bounds (junk masked)
    __builtin_amdgcn_global_load_lds(
        (const __attribute__((address_space(1))) void*)(Dskb + e),
        (__attribute__((address_space(3))) void*)(dst0 + u * 256), 16, 0, 0);
  }
}

// ---------------- Kernel 2: soft-DTW wavefront DP (base-2 domain) ----------
// One block per batch, 4 waves x 64 lanes, 2 adjacent rows per lane.
// Per phase: [DMA next span] -> [vmcnt gate] -> [32x ds_read_b64 into regs]
// -> [32 pure-VALU steps] -> barrier. Recurrence chain: DPP + exp2/log2 only.
extern __shared__ float smem[];
__global__ __launch_bounds__(256) void softdtw_kernel(
    const float* __restrict__ Dsk, float* __restrict__ out) {
  const int b = blockIdx.x;
  const int t = threadIdx.x;
  const int wu = __builtin_amdgcn_readfirstlane(t >> 6);
  const int lane = t & 63;

  float* bufD = smem;                 // [4][2][32][128]
  float* bbuf = smem + BUFD_FLOATS;   // [4][514]: bbuf[w][j] = R'[128w][j]

  for (int k = t; k < BBUF_FLOATS; k += 256) bbuf[k] = BIGF;
  __syncthreads();

  const float* __restrict__ Dskb = Dsk + (size_t)b * DIAGELEMS;

  // Pre-issue DMA for this wave's first span (parity (4wu)&1 == 0).
  dma_span(Dskb, bufD, wu, 4 * wu, lane);

  float ra0 = BIGF, rb0 = BIGF;  // row r0 (i0 = r0+1):  R'[i0][j-1], R'[i0][j-2]
  float ra1 = BIGF, rb1 = BIGF;  // row r0+1
  float old2 = BIGF;             // lane-0 up2 boundary (chained)

  for (int S = 0; S < TPH; ++S) {
    const int c = S - wu;  // this wave's span index this phase
    const bool active = (c >= 4 * wu) && (c <= 4 * wu + SPW - 1) && (c < NSPANS);
    if (active) {
      const int q = c + 1;  // prefetch next span
      const bool issue = (q <= 4 * wu + SPW - 1) && (q < NSPANS);
      if (issue) {
        dma_span(Dskb, bufD, wu, q, lane);
        asm volatile("s_waitcnt vmcnt(16)" ::: "memory");  // span-c DMA done
      } else {
        asm volatile("s_waitcnt vmcnt(0)" ::: "memory");
      }

      const int cc = c - 4 * wu;             // phase-local span index 0..19
      const int jv0 = 32 * cc + 1 - 2 * lane;  // j of cell0 at k=0

      // boundary row segment (lane-0 consumes via readlane; junk masked)
      int bi = 32 * cc + 1 + lane;
      bi = bi > MM + 1 ? MM + 1 : bi;
      const float browA = wu ? bbuf[wu * (MM + 2) + bi] : BIGF;

      const float* myD = bufD + (wu * 2 + (c & 1)) * (CSPAN * 128);
      float2 Dv[CSPAN];
#pragma unroll
      for (int k = 0; k < CSPAN; ++k)
        Dv[k] = *(const float2*)&myD[k * 128 + 2 * lane];

#pragma unroll
      for (int k = 0; k < CSPAN; ++k) {
        // lane-0 boundary values (uniform)
        float o1 = __int_as_float(
            __builtin_amdgcn_readlane(__float_as_int(browA), k));
        float o2 = old2;
        if (k == 0 && wu == 0 && c == 0) o2 = 0.0f;  // R'[0][0]
        old2 = o1;

        // neighbor row (i0-1) values via DPP from lane-1's bottom row
        float up1 = dpp_shr1(ra1, o1);  // R'[i0-1][j]
        float up2 = dpp_shr1(rb1, o2);  // R'[i0-1][j-1]

        const float d0 = Dv[k].x;
        const float d1 = Dv[k].y;

        // row i0 cell
        float m0 = fminf(fminf(up1, up2), ra0);
        float s0 = __builtin_amdgcn_exp2f(m0 - up1) +
                   __builtin_amdgcn_exp2f(m0 - up2) +
                   __builtin_amdgcn_exp2f(m0 - ra0);
        float n0 = d0 + (m0 - __builtin_amdgcn_logf(s0));

        // row i0+1 cell (uses pre-update row-i0 state)
        float m1 = fminf(fminf(ra0, rb0), ra1);
        float s1 = __builtin_amdgcn_exp2f(m1 - ra0) +
                   __builtin_amdgcn_exp2f(m1 - rb0) +
                   __builtin_amdgcn_exp2f(m1 - ra1);
        float n1 = d1 + (m1 - __builtin_amdgcn_logf(s1));

        const int jv = jv0 + k;
        const bool a0 = (unsigned)(jv - 1) < (unsigned)MM;
        const bool a1 = (unsigned)(jv - 2) < (unsigned)MM;

        rb0 = a0 ? ra0 : rb0;
        ra0 = a0 ? n0 : ra0;
        rb1 = a1 ? ra1 : rb1;
        ra1 = a1 ? n1 : ra1;

        // publish boundary row for next wave (row 128(w+1) = lane63's row 2)
        if (wu < WAVES - 1 && lane == 63 && a1)
          bbuf[(wu + 1) * (MM + 2) + (jv - 1)] = n1;
      }
    }
    __syncthreads();
  }

  if (t == 255) out[b] = ra1 * LN2F;  // R'[512][512] -> natural-log domain
}

extern "C" void kernel_launch(void* const* d_in, const int* in_sizes, int n_in,
                              void* d_out, int out_size, void* d_ws,
                              size_t ws_size, hipStream_t stream) {
  const float* X = (const float*)d_in[0];
  const float* Y = (const float*)d_in[1];
  float* out = (float*)d_out;
  float* Dsk = (float*)d_ws;

  const size_t needed = (size_t)NB * DIAGELEMS * sizeof(float);
  if (ws_size < needed) return;

  hipFuncSetAttribute((const void*)softdtw_kernel,
                      hipFuncAttributeMaxDynamicSharedMemorySize, SMEM_BYTES);

  pairdist_kernel<<<dim3(MM / 64, NN / 64, NB), 256, 0, stream>>>(X, Y, Dsk);
  softdtw_kernel<<<NB, 256, SMEM_BYTES, stream>>>(Dsk, out);
}

// Round 5
// 148.890 us; speedup vs baseline: 2.9878x; 1.1573x over previous
//
#include <hip/hip_runtime.h>

#define BIGF 1e30f
#define LOG2E 1.4426950408889634f
#define LN2F 0.6931471805599453f

constexpr int NB = 16;    // batches
constexpr int NN = 512;   // N rows
constexpr int MM = 512;   // M cols
constexpr int KD = 64;    // feature dim
constexpr int WAVES = 8;                     // 512 threads, 1 row/lane
constexpr int CSPAN = 32;                    // diagonals per barrier phase
constexpr int NSPANS = 32;                   // 1023 diagonals / 32
constexpr int SPW = 18;                      // spans per 64-row block
constexpr int TPH = 3 * (WAVES - 1) + SPW;   // 39 barrier phases
constexpr int DIAGELEMS = NN * MM;

constexpr int BBSTRIDE = MM + 2;                      // 514
constexpr int BUFD_FLOATS = WAVES * 2 * CSPAN * 64;   // 32768 (128 KiB)
constexpr int BBUF_FLOATS = WAVES * BBSTRIDE;         // 4112  (16 KiB)
constexpr int SMEM_BYTES = (BUFD_FLOATS + BBUF_FLOATS) * 4;  // 147520

// Packed anti-diagonal layout: element (i,j) [0-based] lives at
// Dsk[b*DIAGELEMS + B(s) + i],  s = i+j.
__device__ __forceinline__ int Bclosed(int s) {
  return (s <= 511) ? (s * (s + 1)) / 2
                    : DIAGELEMS - ((1023 - s) * (1024 - s)) / 2 - (s - 511);
}

// ---------------- Kernel 1: pairwise squared distances (exp2-domain) -------
// Computes 64x64 tile, stages in LDS, stores anti-diagonal-major with
// fully coalesced 64-lane segment stores.
__global__ __launch_bounds__(256) void pairdist_kernel(
    const float* __restrict__ X, const float* __restrict__ Y,
    float* __restrict__ Dsk) {
  const int b = blockIdx.z;
  const int i0 = blockIdx.y * 64;
  const int j0 = blockIdx.x * 64;

  __shared__ float Xs[64][65];
  __shared__ float Ys[64][65];
  __shared__ float Ds[64][66];  // stride 66: diag reads (stride 65) conflict-free

  const float* Xb = X + ((size_t)b * NN + i0) * KD;
  const float* Yb = Y + ((size_t)b * MM + j0) * KD;
  for (int k = threadIdx.x; k < 64 * KD; k += 256) {
    Xs[k >> 6][k & 63] = Xb[k];
    Ys[k >> 6][k & 63] = Yb[k];
  }
  __syncthreads();

  const int tx = threadIdx.x & 15;
  const int ty = threadIdx.x >> 4;
  const int r0 = ty * 4, c0 = tx * 4;

  float acc[4][4];
#pragma unroll
  for (int a = 0; a < 4; ++a)
#pragma unroll
    for (int e = 0; e < 4; ++e) acc[a][e] = 0.0f;

  for (int d = 0; d < KD; ++d) {
    float xv[4], yv[4];
#pragma unroll
    for (int q = 0; q < 4; ++q) xv[q] = Xs[r0 + q][d];
#pragma unroll
    for (int q = 0; q < 4; ++q) yv[q] = Ys[c0 + q][d];
#pragma unroll
    for (int a = 0; a < 4; ++a)
#pragma unroll
      for (int e = 0; e < 4; ++e) {
        float df = xv[a] - yv[e];
        acc[a][e] = fmaf(df, df, acc[a][e]);
      }
  }

#pragma unroll
  for (int a = 0; a < 4; ++a)
#pragma unroll
    for (int e = 0; e < 4; ++e)
      Ds[r0 + a][c0 + e] = fminf(acc[a][e], 10000.0f) * LOG2E;
  __syncthreads();

  // diag-major coalesced stores: wave handles diag sl, 64 lanes = 1 segment
  const int wv = threadIdx.x >> 6;
  const int ln = threadIdx.x & 63;
  float* Db = Dsk + (size_t)b * DIAGELEMS;
  for (int sl = wv; sl < 127; sl += 4) {
    const int istart = sl > 63 ? sl - 63 : 0;
    const int iend = sl < 63 ? sl : 63;
    if (ln <= iend - istart) {
      const int ig = i0 + istart + ln;  // global row
      Db[Bclosed(i0 + j0 + sl) + ig] = Ds[istart + ln][sl - istart - ln];
    }
  }
}

// DPP wave_shr:1 — lane i gets lane i-1's value; lane 0 gets `fill`.
__device__ __forceinline__ float dpp_shr1(float v, float fill) {
  return __int_as_float(__builtin_amdgcn_update_dpp(
      __float_as_int(fill), __float_as_int(v), 0x138 /*WAVE_SHR1*/, 0xf, 0xf,
      false));
}

// DMA one span's D-block (32 steps x 64 rows) for row-block blk into LDS.
// 8 x global_load_lds width-16: lane l covers step 4u+(l>>4),
// rows 64*blk + (l&15)*4 .. +3; LDS float index = 256u + 4*lane (linear).
__device__ __forceinline__ void dma_span(const float* __restrict__ Dskb,
                                         float* bufD, int blk, int q,
                                         int lane) {
  float* dst0 = bufD + (blk * 2 + (q & 1)) * (CSPAN * 64);
  const int rbase = 64 * blk + (lane & 15) * 4;
  const int sub = lane >> 4;
#pragma unroll
  for (int u = 0; u < 8; ++u) {
    int s = 32 * q + 4 * u + sub;
    s = s > 1022 ? 1022 : s;
    int e = Bclosed(s) + rbase;
    e = e > DIAGELEMS - 4 ? DIAGELEMS - 4 : e;  // junk rows masked later
    __builtin_amdgcn_global_load_lds(
        (const __attribute__((address_space(1))) void*)(Dskb + e),
        (__attribute__((address_space(3))) void*)(dst0 + u * 256), 16, 0, 0);
  }
}

// ---------------- Kernel 2: soft-DTW wavefront DP (base-2 domain) ----------
// One block per batch, 8 waves x 64 lanes, 1 row per lane (2 waves/SIMD).
// Row-block assignment blk = 2*(w&3)+(w>>2) so SIMD-sharing waves (w, w+4)
// own adjacent blocks -> overlapping active windows (stall filling).
extern __shared__ float smem[];
__global__ __launch_bounds__(512) void softdtw_kernel(
    const float* __restrict__ Dsk, float* __restrict__ out) {
  const int b = blockIdx.x;
  const int t = threadIdx.x;
  const int wu = __builtin_amdgcn_readfirstlane(t >> 6);
  const int lane = t & 63;
  const int blk = ((wu & 3) << 1) | (wu >> 2);  // row-block 0..7

  float* bufD = smem;                // [8][2][32][64]
  float* bbuf = smem + BUFD_FLOATS;  // [8][514]: bbuf[k][j] = R'[64k][j]

  for (int k = t; k < BBUF_FLOATS; k += 512) bbuf[k] = BIGF;
  __syncthreads();

  const float* __restrict__ Dskb = Dsk + (size_t)b * DIAGELEMS;

  // pre-issue DMA for this block's first span (parity (2*blk)&1 == 0)
  dma_span(Dskb, bufD, blk, 2 * blk, lane);

  const int r = 64 * blk + lane;  // 0-based row; cell row i = r+1
  float ra = BIGF;                // R'[i][j-1]
  // up2 source: previous step's up1 (= R'[i-1][j-1]).  Seed: R'[i-1][0],
  // which is R'[0][0]=0 only for the global first row's lane.
  float up1p = (blk == 0 && lane == 0) ? 0.0f : BIGF;

  for (int S = 0; S < TPH; ++S) {
    const int cc = S - 3 * blk;  // phase-local span index
    if (cc >= 0 && cc < SPW) {
      const int c = cc + 2 * blk;  // global span (<= 31)
      const bool issue = (cc + 1 < SPW);
      if (issue) {
        dma_span(Dskb, bufD, blk, c + 1, lane);
        asm volatile("s_waitcnt vmcnt(8)" ::: "memory");  // span-c DMA done
      } else {
        asm volatile("s_waitcnt vmcnt(0)" ::: "memory");
      }

      // boundary row segment; only lanes 0..31 consumed via readlane
      int bi = 32 * cc + 1 + (lane & 31);
      bi = bi > 513 ? 513 : bi;
      const float browA = blk ? bbuf[blk * BBSTRIDE + bi] : BIGF;

      const float* myD = bufD + (blk * 2 + (c & 1)) * (CSPAN * 64);
      float dv[CSPAN];
#pragma unroll
      for (int k = 0; k < CSPAN; ++k) dv[k] = myD[k * 64 + lane];

      const int jv0 = 32 * c - r + 1;  // column j at k=0
#pragma unroll
      for (int k = 0; k < CSPAN; ++k) {
        const float o1 = __int_as_float(
            __builtin_amdgcn_readlane(__float_as_int(browA), k));
        const float up1 = dpp_shr1(ra, o1);  // R'[i-1][j]
        const float up2 = up1p;              // R'[i-1][j-1]
        up1p = up1;

        const float m = fminf(fminf(up1, up2), ra);
        const float md = __builtin_amdgcn_fmed3f(up1, up2, ra);
        const float mx = fmaxf(fmaxf(up1, up2), ra);
        const float ssum = 1.0f + __builtin_amdgcn_exp2f(m - md) +
                           __builtin_amdgcn_exp2f(m - mx);
        const float n = dv[k] + (m - __builtin_amdgcn_logf(ssum));

        const int jv = jv0 + k;
        const bool a0 = (unsigned)(jv - 1) < (unsigned)MM;
        ra = a0 ? n : ra;

        // publish boundary row for next block (row 64(blk+1) = lane63's row)
        if (blk < WAVES - 1 && lane == 63 && a0)
          bbuf[(blk + 1) * BBSTRIDE + jv] = n;
      }
    }
    __syncthreads();
  }

  if (blk == WAVES - 1 && lane == 63) out[b] = ra * LN2F;  // R'[512][512]
}

extern "C" void kernel_launch(void* const* d_in, const int* in_sizes, int n_in,
                              void* d_out, int out_size, void* d_ws,
                              size_t ws_size, hipStream_t stream) {
  const float* X = (const float*)d_in[0];
  const float* Y = (const float*)d_in[1];
  float* out = (float*)d_out;
  float* Dsk = (float*)d_ws;

  const size_t needed = (size_t)NB * DIAGELEMS * sizeof(float);
  if (ws_size < needed) return;

  hipFuncSetAttribute((const void*)softdtw_kernel,
                      hipFuncAttributeMaxDynamicSharedMemorySize, SMEM_BYTES);

  pairdist_kernel<<<dim3(MM / 64, NN / 64, NB), 256, 0, stream>>>(X, Y, Dsk);
  softdtw_kernel<<<NB, 512, SMEM_BYTES, stream>>>(Dsk, out);
}